// Round 3
// baseline (51.449 us; speedup 1.0000x reference)
//
#include <hip/hip_runtime.h>
#include <math.h>

#define BIGF 1e9f

constexpr int BB = 2, CC = 4, DD = 64, HH = 64, WW = 64;
constexpr int HW   = HH * WW;      // 4096
constexpr int DHW  = DD * HW;      // 262144
constexpr int CDHW = CC * DHW;     // 1048576
constexpr int NTOT = BB * CDHW;    // 2097152
constexpr int NBLK_B = 256;        // kernel B grid: (b, h, half)

// ---------------------------------------------------------------------------
// Kernel A: W-pass (ballot nearest-set-bit) + H-pass (min-plus), per (b,c,d)
// slice; writes dsq in [B,C,D,H,W] layout. Block 0 also zeroes the counter
// used by kernel B's last-block reduction (B is stream-ordered after A).
// ---------------------------------------------------------------------------
__global__ __launch_bounds__(256) void edt_wh(const int* __restrict__ tgt,
                                              float* __restrict__ dsq,
                                              unsigned int* __restrict__ counter) {
    __shared__ int   ti[HW];   // 16 KB targets slice
    __shared__ float fs[HW];   // 16 KB W-pass result
    const int t   = threadIdx.x;
    const int blk = blockIdx.x;
    if (blk == 0 && t == 0)
        __hip_atomic_store(counter, 0u, __ATOMIC_RELAXED, __HIP_MEMORY_SCOPE_AGENT);

    const int lane = t & 63;
    const int wv   = t >> 6;
    const int b = blk >> 8;
    const int c = (blk >> 6) & 3;
    const int d = blk & 63;
    const size_t tb = (size_t)(b * 64 + d) * HW;   // tgt[b][d][:][:]

    #pragma unroll
    for (int k = 0; k < 16; ++k) ti[t + k * 256] = tgt[tb + t + k * 256];
    __syncthreads();

    // W-pass: binary input -> squared distance to nearest lane of class c.
    #pragma unroll
    for (int r = 0; r < 16; ++r) {
        const int h = wv * 16 + r;
        const bool isc = (ti[h * 64 + lane] == c);
        const unsigned long long mask = __ballot(isc);
        const unsigned long long mlo  = mask & (~0ull >> (63 - lane));
        const unsigned long long mhi  = mask & (~0ull << lane);
        int dd = 1000;
        if (mlo) dd = lane - (63 - __builtin_clzll(mlo));
        if (mhi) dd = min(dd, (int)__builtin_ctzll(mhi) - lane);
        fs[h * 64 + lane] = (dd >= 1000) ? BIGF : (float)(dd * dd);
    }
    __syncthreads();

    // H-pass: 4(i) x 4(w) register tile per thread (proven in R1).
    const int wg = (t & 15) * 4;
    const int i0 = (t >> 4) * 4;
    float acc[4][4];
    #pragma unroll
    for (int a = 0; a < 4; ++a)
        #pragma unroll
        for (int k = 0; k < 4; ++k) acc[a][k] = BIGF;

    #pragma unroll 8
    for (int j = 0; j < 64; ++j) {
        const float4 v = *reinterpret_cast<const float4*>(&fs[j * 64 + wg]);
        #pragma unroll
        for (int a = 0; a < 4; ++a) {
            const float diff = (float)(i0 + a - j);
            const float cost = diff * diff;
            acc[a][0] = fminf(acc[a][0], v.x + cost);
            acc[a][1] = fminf(acc[a][1], v.y + cost);
            acc[a][2] = fminf(acc[a][2], v.z + cost);
            acc[a][3] = fminf(acc[a][3], v.w + cost);
        }
    }
    #pragma unroll
    for (int a = 0; a < 4; ++a) {
        const float4 o = make_float4(acc[a][0], acc[a][1], acc[a][2], acc[a][3]);
        *reinterpret_cast<float4*>(&dsq[(size_t)blk * HW + (size_t)(i0 + a) * 64 + wg]) = o;
    }
}

// ---------------------------------------------------------------------------
// Kernel B: block = (b, h, half). Stages dsq[b][0..3][0..63][h][:] (64 KB),
// D min-plus for output rows half*32..half*32+31 of all 4 classes (one class
// per wave), class exchange through LDS, fused softmax*sqrt reduce, block
// partials, last-block deterministic final sum.
// ---------------------------------------------------------------------------
__global__ __launch_bounds__(256) void edt_d_reduce(const float* __restrict__ pred,
                                                    const float* __restrict__ dsq,
                                                    float* __restrict__ partial,
                                                    unsigned int* __restrict__ counter,
                                                    float* __restrict__ out) {
    __shared__ float sl[4 * HW];   // 64 KB
    __shared__ float wsum[4];
    __shared__ int   lastflag;
    const int t    = threadIdx.x;
    const int blk  = blockIdx.x;
    const int b    = blk >> 7;
    const int h    = (blk >> 1) & 63;
    const int half = blk & 1;

    // Stage: sl[c][d][w] = dsq[b][c][d][h][w]  (4096 float4 chunks, 16/thread)
    #pragma unroll
    for (int k = 0; k < 16; ++k) {
        const int id = k * 256 + t;          // (c,d,wq) linear
        const int c  = id >> 10;
        const int dd = (id >> 4) & 63;
        const int wq = id & 15;
        const float4 v = *reinterpret_cast<const float4*>(
            &dsq[((size_t)((b * 4 + c) * 64 + dd)) * HW + h * 64 + wq * 4]);
        *reinterpret_cast<float4*>(&sl[id * 4]) = v;
    }
    __syncthreads();

    // D min-plus: wave ct handles class ct; 8(i) x 4(w) register tile.
    const int lane = t & 63;
    const int ct   = t >> 6;
    const int wg   = (lane & 15) * 4;
    const int rg   = lane >> 4;
    const int ibase = half * 32 + rg * 8;
    float acc[8][4];
    #pragma unroll
    for (int a = 0; a < 8; ++a)
        #pragma unroll
        for (int k = 0; k < 4; ++k) acc[a][k] = BIGF;

    #pragma unroll 4
    for (int j = 0; j < 64; ++j) {
        const float4 v = *reinterpret_cast<const float4*>(&sl[(ct * 64 + j) * 64 + wg]);
        #pragma unroll
        for (int a = 0; a < 8; ++a) {
            const float diff = (float)(ibase + a - j);
            const float cost = diff * diff;
            acc[a][0] = fminf(acc[a][0], v.x + cost);
            acc[a][1] = fminf(acc[a][1], v.y + cost);
            acc[a][2] = fminf(acc[a][2], v.z + cost);
            acc[a][3] = fminf(acc[a][3], v.w + cost);
        }
    }
    __syncthreads();

    // Exchange: sl2[c][row(0..31)][w] (32 KB, reuses sl).
    #pragma unroll
    for (int a = 0; a < 8; ++a) {
        const float4 o = make_float4(acc[a][0], acc[a][1], acc[a][2], acc[a][3]);
        *reinterpret_cast<float4*>(&sl[((ct * 32 + rg * 8 + a)) * 64 + wg]) = o;
    }
    __syncthreads();

    // Fused softmax-weighted reduce: 8 points per thread.
    float vsum = 0.f;
    #pragma unroll
    for (int kk = 0; kk < 8; ++kk) {
        const int p   = kk * 256 + t;        // 0..2047 = (row, w)
        const int row = p >> 6;
        const int w   = p & 63;
        const int dd  = half * 32 + row;
        const size_t pb = ((size_t)(b * 4) * 64 + dd) * HW + h * 64 + w;
        const float p0 = pred[pb],            p1 = pred[pb + (size_t)DHW],
                    p2 = pred[pb + 2 * (size_t)DHW], p3 = pred[pb + 3 * (size_t)DHW];
        const float s0 = sl[(0 * 32 + row) * 64 + w], s1 = sl[(1 * 32 + row) * 64 + w],
                    s2 = sl[(2 * 32 + row) * 64 + w], s3 = sl[(3 * 32 + row) * 64 + w];
        const float m  = fmaxf(fmaxf(p0, p1), fmaxf(p2, p3));
        const float e0 = __expf(p0 - m), e1 = __expf(p1 - m),
                    e2 = __expf(p2 - m), e3 = __expf(p3 - m);
        const float zinv = 1.0f / (e0 + e1 + e2 + e3);
        vsum += (e0 * sqrtf(s0) + e1 * sqrtf(s1) +
                 e2 * sqrtf(s2) + e3 * sqrtf(s3)) * zinv;
    }
    #pragma unroll
    for (int off = 32; off > 0; off >>= 1) vsum += __shfl_down(vsum, off, 64);
    if (lane == 0) wsum[ct] = vsum;
    __syncthreads();
    if (t == 0) partial[blk] = wsum[0] + wsum[1] + wsum[2] + wsum[3];

    // Last-block deterministic final reduction.
    __threadfence();
    if (t == 0) {
        const unsigned int old = atomicAdd(counter, 1u);
        lastflag = (old == NBLK_B - 1) ? 1 : 0;
    }
    __syncthreads();
    if (lastflag) {
        __threadfence();
        if (t < 64) {
            double s = 0.0;
            #pragma unroll
            for (int k = 0; k < 4; ++k)
                s += (double)__hip_atomic_load(&partial[t + k * 64],
                                               __ATOMIC_RELAXED, __HIP_MEMORY_SCOPE_AGENT);
            #pragma unroll
            for (int off = 32; off > 0; off >>= 1) s += __shfl_down(s, off, 64);
            if (t == 0) out[0] = (float)(s / (double)NTOT);
        }
    }
}

// ---------------------------------------------------------------------------
extern "C" void kernel_launch(void* const* d_in, const int* in_sizes, int n_in,
                              void* d_out, int out_size, void* d_ws, size_t ws_size,
                              hipStream_t stream) {
    const float* pred = (const float*)d_in[0];
    const int*   tgt  = (const int*)d_in[1];
    float* out     = (float*)d_out;
    float* dsq     = (float*)d_ws;                       // NTOT floats (8 MB)
    float* partial = dsq + NTOT;                         // NBLK_B floats
    unsigned int* counter = (unsigned int*)(partial + NBLK_B);

    hipLaunchKernelGGL(edt_wh,       dim3(BB * CC * DD), dim3(256), 0, stream,
                       tgt, dsq, counter);
    hipLaunchKernelGGL(edt_d_reduce, dim3(NBLK_B),       dim3(256), 0, stream,
                       pred, dsq, partial, counter, out);
}